// Round 18
// baseline (213.302 us; speedup 1.0000x reference)
//
#include <hip/hip_runtime.h>
#include <math.h>

#define B 4
#define S 1024
#define D 256
#define H 6
#define HD 64
#define NE 3
#define HHD 384
#define ROWS (B*S)
#define MAXN 128

typedef __attribute__((ext_vector_type(8))) short bf8_t;
typedef __attribute__((ext_vector_type(4))) float f32x4;

__device__ __forceinline__ float leaky(float x){ return x > 0.f ? x : 0.2f*x; }

__device__ __forceinline__ unsigned short f2bf(float f){
    union { float f; unsigned int u; } v; v.f = f;
    unsigned int u = v.u;
    return (unsigned short)((u + 0x7FFFu + ((u >> 16) & 1u)) >> 16);
}
__device__ __forceinline__ float bf2f(unsigned short h){
    union { unsigned int u; float f; } v; v.u = ((unsigned int)h) << 16;
    return v.f;
}
__device__ __forceinline__ float blo(unsigned int u){
    union { unsigned int u; float f; } v; v.u = u << 16; return v.f;
}
__device__ __forceinline__ float bhi(unsigned int u){
    union { unsigned int u; float f; } v; v.u = u & 0xffff0000u; return v.f;
}
__device__ __forceinline__ float i2f(int t){
    union { int i; float f; } v; v.i = t; return v.f;
}
__device__ __forceinline__ int f2i(float f){
    union { float f; int i; } v; v.f = f; return v.i;
}

// ---------- block ranges for prep_misc ----------
#define PB_CONV   1024
#define PB_NBR    1024
#define PB_W1     1536
#define PB_W2     1536
#define PB_BW      256
#define PB_ZERO    177
#define PB_ROUTER 1024
#define PB_TOTAL  (PB_CONV + PB_NBR + PB_W1 + PB_W2 + PB_BW + PB_ZERO + PB_ROUTER)
#define NZERO     45088

// All independent prep tasks in one launch (block-range dispatch).
__global__ __launch_bounds__(256) void prep_misc_kernel(
        const float* __restrict__ feature, const float* __restrict__ adj,
        const float* __restrict__ main_W1, const float* __restrict__ dep_W1,
        const float* __restrict__ main_W2, const float* __restrict__ dep_W2,
        const float* __restrict__ blend_W, const float* __restrict__ router_W,
        const int* __restrict__ doc_p, const int* __restrict__ sect_p,
        unsigned short* __restrict__ featbf, short* __restrict__ nbr,
        int4* __restrict__ nbc, unsigned short* __restrict__ w1nk,
        unsigned short* __restrict__ w2nk, unsigned short* __restrict__ bwt,
        float* __restrict__ zbase, float* __restrict__ rmask)
{
    int blk = blockIdx.x, tid = threadIdx.x;
    if (blk < PB_CONV){
        int idx = blk*256 + tid;                       // < ROWS*D/4
        float4 v = ((const float4*)feature)[idx];
        ushort4 o;
        o.x = f2bf(v.x); o.y = f2bf(v.y); o.z = f2bf(v.z); o.w = f2bf(v.w);
        ((ushort4*)featbf)[idx] = o;
        return;
    }
    blk -= PB_CONV;
    if (blk < PB_NBR){
        int wave = tid >> 6, lane = tid & 63;
        int row = blk*4 + wave;
        int b1 = S - *sect_p - *doc_p;
        int b2 = S - *doc_p;
        const float* ar = adj + (size_t)row*S + lane*16;
        float a[16];
        #pragma unroll
        for (int q = 0; q < 4; q++){
            float4 v = ((const float4*)ar)[q];
            a[q*4+0] = v.x; a[q*4+1] = v.y; a[q*4+2] = v.z; a[q*4+3] = v.w;
        }
        int t0 = lane*16;
        int k = 0, c1 = 0, c2 = 0;
        #pragma unroll
        for (int i = 0; i < 16; i++){
            if (a[i] > 0.f){
                k++;
                int t = t0 + i;
                if (t < b1) c1++;
                if (t < b2) c2++;
            }
        }
        int inc = k;
        #pragma unroll
        for (int d = 1; d < 64; d <<= 1){
            int u = __shfl_up(inc, d);
            if (lane >= d) inc += u;
        }
        int off = inc - k;
        int total = __shfl(inc, 63);
        int o = row*MAXN + off;
        #pragma unroll
        for (int i = 0; i < 16; i++){
            if (a[i] > 0.f) nbr[o++] = (short)(t0 + i);
        }
        for (int d = 32; d; d >>= 1){
            c1 += __shfl_down(c1, d);
            c2 += __shfl_down(c2, d);
        }
        if (lane == 0) nbc[row] = make_int4(total, c1, c2, 0);
        return;
    }
    blk -= PB_NBR;
    if (blk < PB_W1){
        int e = blk / 384;
        int idx = (blk - e*384)*256 + tid;             // < HHD*D
        const float* src = (e == 0) ? main_W1 : dep_W1 + (size_t)(e-1)*H*D*HD;
        int n = idx >> 8, k = idx & 255;
        int h = n >> 6, o = n & 63;
        w1nk[(size_t)e*HHD*D + idx] = f2bf(src[(h*D + k)*HD + o]);
        return;
    }
    blk -= PB_W1;
    if (blk < PB_W2){
        int g = blk*256 + tid;                         // < 4*D*HHD
        int e = g / (D*HHD);
        int rem = g - e*(D*HHD);
        int n = rem / HHD, k = rem - n*HHD;
        const float* src = (e == 0) ? main_W2 : dep_W2 + (size_t)(e-1)*HHD*D;
        w2nk[g] = f2bf(src[k*D + n]);
        return;
    }
    blk -= PB_W2;
    if (blk < PB_BW){
        int col = blk, k = tid;
        bwt[col*D + k] = f2bf(blend_W[k*D + col]);
        return;
    }
    blk -= PB_BW;
    if (blk < PB_ZERO){
        int idx = blk*256 + tid;
        if (idx < NZERO) zbase[idx] = 0.f;
        return;
    }
    blk -= PB_ZERO;
    {
        int wave = tid >> 6, lane = tid & 63;
        int row = blk*4 + wave;
        float4 xv = ((const float4*)(feature + (size_t)row*D))[lane];
        int f = lane*4;
        float xa[4] = {xv.x, xv.y, xv.z, xv.w};
        float p0 = 0.f, p1 = 0.f, p2 = 0.f;
        #pragma unroll
        for (int j = 0; j < 4; j++){
            p0 += xa[j]*router_W[(f+j)*NE + 0];
            p1 += xa[j]*router_W[(f+j)*NE + 1];
            p2 += xa[j]*router_W[(f+j)*NE + 2];
        }
        for (int off = 32; off; off >>= 1){
            p0 += __shfl_down(p0, off);
            p1 += __shfl_down(p1, off);
            p2 += __shfl_down(p2, off);
        }
        if (lane == 0){
            float p[3] = {p0, p1, p2};
            int ex = 0;
            for (int e = 1; e < NE; e++) if (p[e] <= p[ex]) ex = e;
            for (int e = 0; e < NE; e++) rmask[e*ROWS + row] = (e == ex) ? 0.f : 1.f;
        }
    }
}

// ---------- GEMM1 (x@W1) + fused es/ed + colmean; 128-wide M-tile (2 heads/block) ----------
// grid (3, ROWS/64, 5). z<4: expert slices; z==4: blend gate (x<2).
__global__ __launch_bounds__(256, 4) void gemm1_kernel(const unsigned short* __restrict__ w1nk,
                                                    const unsigned short* __restrict__ featbf,
                                                    const float* __restrict__ rmask,
                                                    const float* __restrict__ main_a1s,
                                                    const float* __restrict__ main_a1d,
                                                    const float* __restrict__ dep_a1s,
                                                    const float* __restrict__ dep_a1d,
                                                    const unsigned short* __restrict__ bwt,
                                                    const float* __restrict__ bb,
                                                    unsigned short* __restrict__ htn4,
                                                    float* __restrict__ es8,
                                                    float* __restrict__ ed8,
                                                    float* __restrict__ meanV1p,
                                                    float* __restrict__ gatebuf,
                                                    float* __restrict__ sumBuf){
    __shared__ float ep[2][2][64][17];      // [head][s/d][n][m-chunk]
    int tid = threadIdx.x, wave = tid >> 6, lane = tid & 63;
    int quad = lane >> 4, l16 = lane & 15;
    int e = blockIdx.z;
    int n0 = blockIdx.y*64;
    f32x4 z4 = {0.f,0.f,0.f,0.f};
    bf8_t bz = {0,0,0,0,0,0,0,0};

    if (e == 4){
        // ---- blend gate GEMM: gate[row][col] = sigmoid(x@blend_W + b), 128-wide m ----
        if (blockIdx.x >= 2) return;
        int m0 = blockIdx.x*128;
        const unsigned short* arow0 = bwt + (size_t)(m0 + wave*16 + l16)*D + quad*8;
        const unsigned short* arow1 = arow0 + (size_t)64*D;
        const unsigned short* brow[4];
        #pragma unroll
        for (int j = 0; j < 4; j++)
            brow[j] = featbf + (size_t)(n0 + j*16 + l16)*D + quad*8;
        f32x4 acc[8] = {z4, z4, z4, z4, z4, z4, z4, z4};
        bf8_t a0F = *(const bf8_t*)(arow0);
        bf8_t a1F = *(const bf8_t*)(arow1);
        bf8_t bF[4];
        #pragma unroll
        for (int j = 0; j < 4; j++) bF[j] = *(const bf8_t*)(brow[j]);
        #pragma unroll
        for (int it = 0; it < D/32; it++){
            bf8_t a0C = a0F, a1C = a1F;
            bf8_t bC[4] = {bF[0], bF[1], bF[2], bF[3]};
            if (it + 1 < D/32){
                int kn = (it + 1)*32;
                a0F = *(const bf8_t*)(arow0 + kn);
                a1F = *(const bf8_t*)(arow1 + kn);
                #pragma unroll
                for (int j = 0; j < 4; j++) bF[j] = *(const bf8_t*)(brow[j] + kn);
            }
            #pragma unroll
            for (int j = 0; j < 4; j++){
                acc[j]   = __builtin_amdgcn_mfma_f32_16x16x32_bf16(a0C, bC[j], acc[j],   0, 0, 0);
                acc[4+j] = __builtin_amdgcn_mfma_f32_16x16x32_bf16(a1C, bC[j], acc[4+j], 0, 0, 0);
            }
        }
        int mbase0 = m0 + wave*16 + quad*4;
        int mbase1 = mbase0 + 64;
        float bias0[4], bias1[4];
        #pragma unroll
        for (int r = 0; r < 4; r++){ bias0[r] = bb[mbase0 + r]; bias1[r] = bb[mbase1 + r]; }
        float lsum = 0.f;
        #pragma unroll
        for (int j = 0; j < 4; j++){
            int rown = n0 + j*16 + l16;
            f32x4 st0, st1;
            #pragma unroll
            for (int r = 0; r < 4; r++){
                float g0 = 1.f/(1.f + __expf(-(acc[j][r] + bias0[r])));
                float g1 = 1.f/(1.f + __expf(-(acc[4+j][r] + bias1[r])));
                lsum += g0 + g1;
                st0[r] = g0; st1[r] = g1;
            }
            *(f32x4*)(gatebuf + (size_t)rown*D + mbase0) = st0;
            *(f32x4*)(gatebuf + (size_t)rown*D + mbase1) = st1;
        }
        float* redp = &ep[0][0][0][0];
        redp[tid] = lsum;
        __syncthreads();
        for (int sft = 128; sft; sft >>= 1){
            if (tid < sft) redp[tid] += redp[tid + sft];
            __syncthreads();
        }
        if (tid == 0) atomicAdd(sumBuf, redp[0]);
        return;
    }

    // ---- expert slice: head pair p -> heads 2p, 2p+1 ----
    int p = blockIdx.x;
    int m0 = p*128;
    const unsigned short* arow0 = w1nk + (size_t)e*HHD*D + (size_t)(m0 + wave*16 + l16)*D + quad*8;
    const unsigned short* arow1 = arow0 + (size_t)64*D;
    const unsigned short* brow[4];
    bool zr[4];
    #pragma unroll
    for (int j = 0; j < 4; j++){
        int n = n0 + j*16 + l16;
        brow[j] = featbf + (size_t)n*D + quad*8;
        zr[j] = (e > 0) ? (rmask[(size_t)(e-1)*ROWS + n] == 0.f) : false;
    }
    f32x4 acc[8] = {z4, z4, z4, z4, z4, z4, z4, z4};
    bf8_t a0F = *(const bf8_t*)(arow0);
    bf8_t a1F = *(const bf8_t*)(arow1);
    bf8_t bF[4];
    #pragma unroll
    for (int j = 0; j < 4; j++) bF[j] = zr[j] ? bz : *(const bf8_t*)(brow[j]);
    #pragma unroll
    for (int it = 0; it < D/32; it++){
        bf8_t a0C = a0F, a1C = a1F;
        bf8_t bC[4] = {bF[0], bF[1], bF[2], bF[3]};
        if (it + 1 < D/32){
            int kn = (it + 1)*32;
            a0F = *(const bf8_t*)(arow0 + kn);
            a1F = *(const bf8_t*)(arow1 + kn);
            #pragma unroll
            for (int j = 0; j < 4; j++) bF[j] = zr[j] ? bz : *(const bf8_t*)(brow[j] + kn);
        }
        #pragma unroll
        for (int j = 0; j < 4; j++){
            acc[j]   = __builtin_amdgcn_mfma_f32_16x16x32_bf16(a0C, bC[j], acc[j],   0, 0, 0);
            acc[4+j] = __builtin_amdgcn_mfma_f32_16x16x32_bf16(a1C, bC[j], acc[4+j], 0, 0, 0);
        }
    }
    int b = n0 >> 10;
    int mbase0 = m0 + wave*16 + quad*4;
    int mbase1 = mbase0 + 64;
    int obase = wave*16 + quad*4;   // o within head (0..63)
    int h0 = p*2, h1 = p*2 + 1;
    #pragma unroll
    for (int j = 0; j < 4; j++){
        int row = n0 + j*16 + l16;
        ushort4 o0, o1;
        o0.x = f2bf(acc[j][0]);   o0.y = f2bf(acc[j][1]);
        o0.z = f2bf(acc[j][2]);   o0.w = f2bf(acc[j][3]);
        o1.x = f2bf(acc[4+j][0]); o1.y = f2bf(acc[4+j][1]);
        o1.z = f2bf(acc[4+j][2]); o1.w = f2bf(acc[4+j][3]);
        *(ushort4*)(htn4 + ((size_t)e*ROWS + row)*HHD + mbase0) = o0;
        *(ushort4*)(htn4 + ((size_t)e*ROWS + row)*HHD + mbase1) = o1;
    }
    const float* a1sp = (e == 0) ? main_a1s : dep_a1s + (size_t)(e-1)*H*HD;
    const float* a1dp = (e == 0) ? main_a1d : dep_a1d + (size_t)(e-1)*H*HD;
    float s0v[4], d0v[4], s1v[4], d1v[4];
    #pragma unroll
    for (int r = 0; r < 4; r++){
        s0v[r] = a1sp[mbase0 + r]; d0v[r] = a1dp[mbase0 + r];
        s1v[r] = a1sp[mbase1 + r]; d1v[r] = a1dp[mbase1 + r];
    }
    #pragma unroll
    for (int j = 0; j < 4; j++){
        float ps0 = 0.f, pd0 = 0.f, ps1 = 0.f, pd1 = 0.f;
        #pragma unroll
        for (int r = 0; r < 4; r++){
            ps0 += acc[j][r]*s0v[r];   pd0 += acc[j][r]*d0v[r];
            ps1 += acc[4+j][r]*s1v[r]; pd1 += acc[4+j][r]*d1v[r];
        }
        ep[0][0][j*16 + l16][wave*4 + quad] = ps0;
        ep[0][1][j*16 + l16][wave*4 + quad] = pd0;
        ep[1][0][j*16 + l16][wave*4 + quad] = ps1;
        ep[1][1][j*16 + l16][wave*4 + quad] = pd1;
    }
    float* mvb = meanV1p + ((size_t)e*B + b)*512;
    #pragma unroll
    for (int r = 0; r < 4; r++){
        float cm0 = acc[0][r] + acc[1][r] + acc[2][r] + acc[3][r];
        float cm1 = acc[4][r] + acc[5][r] + acc[6][r] + acc[7][r];
        for (int off = 8; off; off >>= 1){
            cm0 += __shfl_down(cm0, off, 16);
            cm1 += __shfl_down(cm1, off, 16);
        }
        if (l16 == 0){
            atomicAdd(mvb + (obase + r)*8 + h0, cm0*(1.f/(float)S));
            atomicAdd(mvb + (obase + r)*8 + h1, cm1*(1.f/(float)S));
        }
    }
    __syncthreads();
    {
        int hh = tid >> 7, arr = (tid >> 6) & 1, sl = tid & 63;
        float sum = 0.f;
        #pragma unroll
        for (int i = 0; i < 16; i++) sum += ep[hh][arr][sl][i];
        int n = n0 + sl;
        float* dst = arr ? ed8 : es8;
        dst[(((size_t)e*B + (n >> 10))*S + (n & 1023))*8 + (p*2 + hh)] = sum;
    }
}

// ---------- attn1 gather: one wave per (e,b,s), all 6 heads, direct htn4 reads ----------
// grid (S/4, 16)
__global__ __launch_bounds__(256) void attn1_gather_kernel(const unsigned short* __restrict__ htn4,
                                                           const float* __restrict__ es8,
                                                           const float* __restrict__ ed8,
                                                           const short* __restrict__ nbr,
                                                           const int4* __restrict__ nbc,
                                                           const float* __restrict__ meanV1p,
                                                           unsigned short* __restrict__ h1c4){
    __shared__ float wrec[4][MAXN][8];     // 16 KB
    int wave = threadIdx.x >> 6, lane = threadIdx.x & 63;
    int s = blockIdx.x*4 + wave;
    int e = blockIdx.y >> 2, b = blockIdx.y & 3;
    int row = b*S + s;
    int4 c = nbc[row];
    int lo = 0, hi = c.x;
    if (e == 1) hi = c.y;
    else if (e == 2){ lo = c.y; hi = c.z; }
    else if (e == 3){ lo = c.z; }
    int nn = hi - lo;
    const float* esp = es8 + (((size_t)e*B + b)*S + s)*8;
    f32x4 es_lo = *(const f32x4*)esp;
    f32x4 es_hi = *(const f32x4*)(esp + 4);
    float esv[6] = {es_lo[0], es_lo[1], es_lo[2], es_lo[3], es_hi[0], es_hi[1]};
    const float* edb = ed8 + (((size_t)e*B + b)*S)*8;
    const short* nl = nbr + (size_t)row*MAXN;
    float w0[6] = {0,0,0,0,0,0}, w1[6] = {0,0,0,0,0,0};
    int t0 = 0, t1 = 0;
    if (lane < nn){
        t0 = nl[lo + lane];
        const float* ep = edb + (size_t)t0*8;
        f32x4 d0 = *(const f32x4*)ep;
        f32x4 d1 = *(const f32x4*)(ep + 4);
        float edv[6] = {d0[0], d0[1], d0[2], d0[3], d1[0], d1[1]};
        #pragma unroll
        for (int h = 0; h < 6; h++) w0[h] = __expf(leaky(esv[h] + edv[h]));
    }
    if (64 + lane < nn){
        t1 = nl[lo + 64 + lane];
        const float* ep = edb + (size_t)t1*8;
        f32x4 d0 = *(const f32x4*)ep;
        f32x4 d1 = *(const f32x4*)(ep + 4);
        float edv[6] = {d0[0], d0[1], d0[2], d0[3], d1[0], d1[1]};
        #pragma unroll
        for (int h = 0; h < 6; h++) w1[h] = __expf(leaky(esv[h] + edv[h]));
    }
    float den[6];
    #pragma unroll
    for (int h = 0; h < 6; h++){
        float d = w0[h] + w1[h];
        for (int o2 = 32; o2; o2 >>= 1) d += __shfl_down(d, o2);
        den[h] = __shfl(d, 0);
    }
    if (lane < nn){
        f32x4 r0 = {w0[0], w0[1], w0[2], w0[3]};
        f32x4 r1 = {w0[4], w0[5], i2f(t0), 0.f};
        *(f32x4*)&wrec[wave][lane][0] = r0;
        *(f32x4*)&wrec[wave][lane][4] = r1;
    }
    if (64 + lane < nn){
        f32x4 r0 = {w1[0], w1[1], w1[2], w1[3]};
        f32x4 r1 = {w1[4], w1[5], i2f(t1), 0.f};
        *(f32x4*)&wrec[wave][64 + lane][0] = r0;
        *(f32x4*)&wrec[wave][64 + lane][4] = r1;
    }
    // direct htn4 reads: per neighbor, 6 coalesced 128B loads (imm offsets h*64)
    const unsigned short* Vb = htn4 + ((size_t)e*ROWS + b*S)*HHD + lane;
    float acc[6] = {0,0,0,0,0,0};
    #pragma unroll 4
    for (int j = 0; j < nn; j++){
        f32x4 r0 = *(const f32x4*)&wrec[wave][j][0];
        f32x4 r1 = *(const f32x4*)&wrec[wave][j][4];
        int t = f2i(r1[2]);
        const unsigned short* vp = Vb + (size_t)t*HHD;
        float v0 = bf2f(vp[0]);
        float v1 = bf2f(vp[64]);
        float v2 = bf2f(vp[128]);
        float v3 = bf2f(vp[192]);
        float v4 = bf2f(vp[256]);
        float v5 = bf2f(vp[320]);
        acc[0] += r0[0]*v0; acc[1] += r0[1]*v1;
        acc[2] += r0[2]*v2; acc[3] += r0[3]*v3;
        acc[4] += r1[0]*v4; acc[5] += r1[1]*v5;
    }
    unsigned short* outp = h1c4 + ((size_t)e*ROWS + row)*HHD;
    const float* mv = meanV1p + ((size_t)e*B + b)*512 + lane*8;
    #pragma unroll
    for (int h = 0; h < 6; h++){
        float v = (nn > 0) ? acc[h]/den[h] : mv[h];
        v = v > 0.f ? v : __expf(v) - 1.f;   // ELU
        outp[h*64 + lane] = f2bf(v);
    }
}

// ---------- GEMM2 (h1@W2) + fused f2s/f2d + colmean; 128-wide M-tile ----------
// grid (D/128=2, ROWS/64, 4experts). launch_bounds(256,4) + pipelined K-loop.
__global__ __launch_bounds__(256, 4) void gemm2_kernel(const unsigned short* __restrict__ w2nk,
                                                    const unsigned short* __restrict__ h1c4,
                                                    const float* __restrict__ main_a2s,
                                                    const float* __restrict__ main_a2d,
                                                    const float* __restrict__ dep_a2s,
                                                    const float* __restrict__ dep_a2d,
                                                    unsigned short* __restrict__ h2n4,
                                                    float* __restrict__ f2s4,
                                                    float* __restrict__ f2d4,
                                                    float* __restrict__ meanV2){
    __shared__ float ep[2][2][64][17];     // [m-half][s/d][n][m-chunk]
    int tid = threadIdx.x, wave = tid >> 6, lane = tid & 63;
    int quad = lane >> 4, l16 = lane & 15;
    int e = blockIdx.z;
    int m0 = blockIdx.x*128;
    int n0 = blockIdx.y*64;
    f32x4 z4 = {0.f,0.f,0.f,0.f};
    const unsigned short* arow0 = w2nk + (size_t)e*D*HHD + (size_t)(m0 + wave*16 + l16)*HHD + quad*8;
    const unsigned short* arow1 = arow0 + (size_t)64*HHD;
    const unsigned short* brow[4];
    #pragma unroll
    for (int j = 0; j < 4; j++)
        brow[j] = h1c4 + (size_t)e*ROWS*HHD + (size_t)(n0 + j*16 + l16)*HHD + quad*8;
    f32x4 acc[8] = {z4, z4, z4, z4, z4, z4, z4, z4};
    bf8_t a0F = *(const bf8_t*)(arow0);
    bf8_t a1F = *(const bf8_t*)(arow1);
    bf8_t bF[4];
    #pragma unroll
    for (int j = 0; j < 4; j++) bF[j] = *(const bf8_t*)(brow[j]);
    #pragma unroll
    for (int it = 0; it < HHD/32; it++){
        bf8_t a0C = a0F, a1C = a1F;
        bf8_t bC[4] = {bF[0], bF[1], bF[2], bF[3]};
        if (it + 1 < HHD/32){
            int kn = (it + 1)*32;
            a0F = *(const bf8_t*)(arow0 + kn);
            a1F = *(const bf8_t*)(arow1 + kn);
            #pragma unroll
            for (int j = 0; j < 4; j++) bF[j] = *(const bf8_t*)(brow[j] + kn);
        }
        #pragma unroll
        for (int j = 0; j < 4; j++){
            acc[j]   = __builtin_amdgcn_mfma_f32_16x16x32_bf16(a0C, bC[j], acc[j],   0, 0, 0);
            acc[4+j] = __builtin_amdgcn_mfma_f32_16x16x32_bf16(a1C, bC[j], acc[4+j], 0, 0, 0);
        }
    }
    int b = n0 >> 10;
    int mbase0 = m0 + wave*16 + quad*4;
    int mbase1 = mbase0 + 64;
    #pragma unroll
    for (int j = 0; j < 4; j++){
        int row = n0 + j*16 + l16;
        ushort4 o0, o1;
        o0.x = f2bf(acc[j][0]);   o0.y = f2bf(acc[j][1]);
        o0.z = f2bf(acc[j][2]);   o0.w = f2bf(acc[j][3]);
        o1.x = f2bf(acc[4+j][0]); o1.y = f2bf(acc[4+j][1]);
        o1.z = f2bf(acc[4+j][2]); o1.w = f2bf(acc[4+j][3]);
        *(ushort4*)(h2n4 + ((size_t)e*ROWS + row)*D + mbase0) = o0;
        *(ushort4*)(h2n4 + ((size_t)e*ROWS + row)*D + mbase1) = o1;
    }
    const float* a2sp = (e == 0) ? main_a2s : dep_a2s + (size_t)(e-1)*D;
    const float* a2dp = (e == 0) ? main_a2d : dep_a2d + (size_t)(e-1)*D;
    float s0v[4], d0v[4], s1v[4], d1v[4];
    #pragma unroll
    for (int r = 0; r < 4; r++){
        s0v[r] = a2sp[mbase0 + r]; d0v[r] = a2dp[mbase0 + r];
        s1v[r] = a2sp[mbase1 + r]; d1v[r] = a2dp[mbase1 + r];
    }
    #pragma unroll
    for (int j = 0; j < 4; j++){
        float ps0 = 0.f, pd0 = 0.f, ps1 = 0.f, pd1 = 0.f;
        #pragma unroll
        for (int r = 0; r < 4; r++){
            ps0 += acc[j][r]*s0v[r];   pd0 += acc[j][r]*d0v[r];
            ps1 += acc[4+j][r]*s1v[r]; pd1 += acc[4+j][r]*d1v[r];
        }
        ep[0][0][j*16 + l16][wave*4 + quad] = ps0;
        ep[0][1][j*16 + l16][wave*4 + quad] = pd0;
        ep[1][0][j*16 + l16][wave*4 + quad] = ps1;
        ep[1][1][j*16 + l16][wave*4 + quad] = pd1;
    }
    #pragma unroll
    for (int r = 0; r < 4; r++){
        float cm0 = acc[0][r] + acc[1][r] + acc[2][r] + acc[3][r];
        float cm1 = acc[4][r] + acc[5][r] + acc[6][r] + acc[7][r];
        for (int off = 8; off; off >>= 1){
            cm0 += __shfl_down(cm0, off, 16);
            cm1 += __shfl_down(cm1, off, 16);
        }
        if (l16 == 0){
            atomicAdd(meanV2 + ((size_t)e*B + b)*D + mbase0 + r, cm0*(1.f/(float)S));
            atomicAdd(meanV2 + ((size_t)e*B + b)*D + mbase1 + r, cm1*(1.f/(float)S));
        }
    }
    __syncthreads();
    {
        int hh = tid >> 7, arr = (tid >> 6) & 1, sl = tid & 63;
        float sum = 0.f;
        #pragma unroll
        for (int i = 0; i < 16; i++) sum += ep[hh][arr][sl][i];
        int n = n0 + sl;
        float* dst = arr ? f2d4 : f2s4;
        atomicAdd(dst + (size_t)e*ROWS + n, sum);
    }
}

// ---------- generic per-wave gather over a neighbor sub-range ----------
__device__ __forceinline__ void gather_range(const unsigned short* __restrict__ V,
                                             const float* __restrict__ fdp,
                                             float fs_r,
                                             const short* __restrict__ nl,
                                             int lo, int hi,
                                             float2* __restrict__ wr, int lane,
                                             float acc[4], float& den){
    int cnt = hi - lo;
    float w0 = 0.f, w1 = 0.f;
    int t0 = 0, t1 = 0;
    if (lane < cnt){ t0 = nl[lo + lane]; w0 = __expf(leaky(fs_r + fdp[t0])); }
    if (64 + lane < cnt){ t1 = nl[lo + 64 + lane]; w1 = __expf(leaky(fs_r + fdp[t1])); }
    float d = w0 + w1;
    for (int o2 = 32; o2; o2 >>= 1) d += __shfl_down(d, o2);
    den = __shfl(d, 0);
    if (lane < cnt){ float2 r; r.x = w0; r.y = i2f(t0); wr[lane] = r; }
    if (64 + lane < cnt){ float2 r; r.x = w1; r.y = i2f(t1); wr[64 + lane] = r; }
    acc[0] = acc[1] = acc[2] = acc[3] = 0.f;
    #pragma unroll 4
    for (int j = 0; j < cnt; j++){
        float2 r = wr[j];
        float w = r.x;
        int t = f2i(r.y);
        const unsigned short* vp = V + (size_t)t*D + lane*4;
        uint2 dv = *(const uint2*)vp;
        acc[0] += w*blo(dv.x); acc[1] += w*bhi(dv.x);
        acc[2] += w*blo(dv.y); acc[3] += w*bhi(dv.y);
    }
}

// ---------- attn2 + blend: one block per (b,s); wave-balanced expert split ----------
// w0/w1: main expert halves; w2: e1; w3: e2 then e3. Combine in LDS.
// grid (S, B)
__global__ __launch_bounds__(256) void attn2_blend_kernel(const unsigned short* __restrict__ h2n4,
                                                          const float* __restrict__ f2s4,
                                                          const float* __restrict__ f2d4,
                                                          const short* __restrict__ nbr,
                                                          const int4* __restrict__ nbc,
                                                          const float* __restrict__ meanV2,
                                                          const float* __restrict__ gatebuf,
                                                          const float* __restrict__ rmask,
                                                          const float* __restrict__ sumBuf,
                                                          float* __restrict__ outp){
    __shared__ float2 wrec[4][MAXN];       // 4 KB
    __shared__ float paccs[5][256];        // 5 KB: {e0a, e0b, e1, e2, e3}
    __shared__ float pden[5];
    int wave = threadIdx.x >> 6, lane = threadIdx.x & 63;
    int s = blockIdx.x, b = blockIdx.y;
    int row = b*S + s;
    int4 c = nbc[row];
    const short* nl = nbr + (size_t)row*MAXN;
    float acc[4]; float den;
    if (wave == 0 || wave == 1){
        // main expert (e0) split in half
        int mid = c.x >> 1;
        int lo = (wave == 0) ? 0 : mid;
        int hi = (wave == 0) ? mid : c.x;
        float fs_r = f2s4[row];
        const float* fdp = f2d4 + b*S;
        const unsigned short* V = h2n4 + (size_t)(b*S)*D;
        gather_range(V, fdp, fs_r, nl, lo, hi, wrec[wave], lane, acc, den);
        #pragma unroll
        for (int q = 0; q < 4; q++) paccs[wave][lane*4 + q] = acc[q];
        if (lane == 0) pden[wave] = den;
    } else if (wave == 2){
        // e1: range [0, c.y)
        float fs_r = f2s4[(size_t)1*ROWS + row];
        const float* fdp = f2d4 + (size_t)1*ROWS + b*S;
        const unsigned short* V = h2n4 + ((size_t)1*ROWS + b*S)*D;
        gather_range(V, fdp, fs_r, nl, 0, c.y, wrec[2], lane, acc, den);
        #pragma unroll
        for (int q = 0; q < 4; q++) paccs[2][lane*4 + q] = acc[q];
        if (lane == 0) pden[2] = den;
    } else {
        // e2: [c.y, c.z), then e3: [c.z, c.x)
        {
            float fs_r = f2s4[(size_t)2*ROWS + row];
            const float* fdp = f2d4 + (size_t)2*ROWS + b*S;
            const unsigned short* V = h2n4 + ((size_t)2*ROWS + b*S)*D;
            gather_range(V, fdp, fs_r, nl, c.y, c.z, wrec[3], lane, acc, den);
            #pragma unroll
            for (int q = 0; q < 4; q++) paccs[3][lane*4 + q] = acc[q];
            if (lane == 0) pden[3] = den;
        }
        {
            float fs_r = f2s4[(size_t)3*ROWS + row];
            const float* fdp = f2d4 + (size_t)3*ROWS + b*S;
            const unsigned short* V = h2n4 + ((size_t)3*ROWS + b*S)*D;
            gather_range(V, fdp, fs_r, nl, c.z, c.x, wrec[3], lane, acc, den);
            #pragma unroll
            for (int q = 0; q < 4; q++) paccs[4][lane*4 + q] = acc[q];
            if (lane == 0) pden[4] = den;
        }
    }
    __syncthreads();
    // combine: thread tid = col
    int col = threadIdx.x;
    int nn1 = c.y, nn2 = c.z - c.y, nn3 = c.x - c.z;
    float o0 = (c.x > 0) ? (paccs[0][col] + paccs[1][col])/(pden[0] + pden[1])
                         : meanV2[(size_t)b*D + col];
    float o1 = (nn1 > 0) ? paccs[2][col]/pden[2] : meanV2[((size_t)1*B + b)*D + col];
    float o2 = (nn2 > 0) ? paccs[3][col]/pden[3] : meanV2[((size_t)2*B + b)*D + col];
    float o3 = (nn3 > 0) ? paccs[4][col]/pden[4] : meanV2[((size_t)3*B + b)*D + col];
    float g = gatebuf[(size_t)row*D + col];
    float dep = rmask[row]*o1 + rmask[ROWS + row]*o2 + rmask[2*ROWS + row]*o3;
    outp[(size_t)row*D + col] = g*o0 + (1.f - g)*dep;
    if (blockIdx.x == 0 && blockIdx.y == 0 && threadIdx.x == 0){
        float mc = sumBuf[0] / (float)(ROWS*D);   // filled during gemm1 gate pass
        outp[ROWS*D]     = fabsf(mc - 0.6f)*0.01f;
        outp[ROWS*D + 1] = mc;
    }
}

extern "C" void kernel_launch(void* const* d_in, const int* in_sizes, int n_in,
                              void* d_out, int out_size, void* d_ws, size_t ws_size,
                              hipStream_t stream)
{
    const float* feature  = (const float*)d_in[0];
    const float* adj      = (const float*)d_in[1];
    const float* main_W1  = (const float*)d_in[2];
    const float* main_a1s = (const float*)d_in[3];
    const float* main_a1d = (const float*)d_in[4];
    const float* main_W2  = (const float*)d_in[5];
    const float* main_a2s = (const float*)d_in[6];
    const float* main_a2d = (const float*)d_in[7];
    const float* dep_W1   = (const float*)d_in[8];
    const float* dep_a1s  = (const float*)d_in[9];
    const float* dep_a1d  = (const float*)d_in[10];
    const float* dep_W2   = (const float*)d_in[11];
    const float* dep_a2s  = (const float*)d_in[12];
    const float* dep_a2d  = (const float*)d_in[13];
    const float* router_W = (const float*)d_in[14];
    const float* blend_W  = (const float*)d_in[15];
    const float* blend_b  = (const float*)d_in[16];
    const int*   doc_p    = (const int*)d_in[17];
    const int*   sect_p   = (const int*)d_in[18];

    char* ws = (char*)d_ws;
    size_t off = 0;
    unsigned short* featbf = (unsigned short*)(ws + off); off += (size_t)ROWS*D*2;        // 2 MB
    short*          nbr    = (short*)(ws + off);          off += (size_t)ROWS*MAXN*2;     // 1 MB
    int4*           nbc    = (int4*)(ws + off);           off += (size_t)ROWS*16;         // 64 KB
    unsigned short* w1nk   = (unsigned short*)(ws + off); off += (size_t)4*HHD*D*2;
    unsigned short* w2nk   = (unsigned short*)(ws + off); off += (size_t)4*D*HHD*2;
    unsigned short* bwt    = (unsigned short*)(ws + off); off += (size_t)D*D*2;
    float* es8 = (float*)(ws + off); off += (size_t)4*B*S*8*4;   // 512 KB
    float* ed8 = (float*)(ws + off); off += (size_t)4*B*S*8*4;   // 512 KB
    float* gatebuf = (float*)(ws + off); off += (size_t)ROWS*D*4;                         // 4 MB
    // region A: htn (12 MB)
    unsigned short* htn4 = (unsigned short*)(ws + off); off += (size_t)4*ROWS*HHD*2;
    // region C: h2n4 (8 MB)
    unsigned short* h2n4 = (unsigned short*)(ws + off); off += (size_t)4*ROWS*D*2;
    unsigned short* h1c4 = (unsigned short*)(ws + off); off += (size_t)4*ROWS*HHD*2;      // 12 MB
    // contiguous zero region (NZERO floats):
    float* f2s4    = (float*)(ws + off); off += (size_t)4*ROWS*4;
    float* f2d4    = (float*)(ws + off); off += (size_t)4*ROWS*4;
    float* meanV1p = (float*)(ws + off); off += (size_t)4*B*512*4;
    float* meanV2  = (float*)(ws + off); off += (size_t)4*B*D*4;
    float* sumBuf  = (float*)(ws + off); off += 128;
    float* rmask   = (float*)(ws + off); off += (size_t)NE*ROWS*4;
    float* outp    = (float*)d_out;

    prep_misc_kernel<<<PB_TOTAL, 256, 0, stream>>>(
        feature, adj, main_W1, dep_W1, main_W2, dep_W2, blend_W, router_W,
        doc_p, sect_p, featbf, nbr, nbc, w1nk, w2nk, bwt, f2s4, rmask);

    gemm1_kernel<<<dim3(3, ROWS/64, 5), 256, 0, stream>>>(w1nk, featbf, rmask,
        main_a1s, main_a1d, dep_a1s, dep_a1d, bwt, blend_b,
        htn4, es8, ed8, meanV1p, gatebuf, sumBuf);
    attn1_gather_kernel<<<dim3(S/4, 16), 256, 0, stream>>>(htn4, es8, ed8, nbr, nbc,
        meanV1p, h1c4);
    gemm2_kernel<<<dim3(D/128, ROWS/64, 4), 256, 0, stream>>>(w2nk, h1c4,
        main_a2s, main_a2d, dep_a2s, dep_a2d, h2n4, f2s4, f2d4, meanV2);
    attn2_blend_kernel<<<dim3(S, B), 256, 0, stream>>>(h2n4, f2s4, f2d4, nbr, nbc,
        meanV2, gatebuf, rmask, sumBuf, outp);
}

// Round 19
// 207.878 us; speedup vs baseline: 1.0261x; 1.0261x over previous
//
#include <hip/hip_runtime.h>
#include <math.h>

#define B 4
#define S 1024
#define D 256
#define H 6
#define HD 64
#define NE 3
#define HHD 384
#define ROWS (B*S)
#define MAXN 128

typedef __attribute__((ext_vector_type(8))) short bf8_t;
typedef __attribute__((ext_vector_type(4))) float f32x4;

__device__ __forceinline__ float leaky(float x){ return x > 0.f ? x : 0.2f*x; }

__device__ __forceinline__ unsigned short f2bf(float f){
    union { float f; unsigned int u; } v; v.f = f;
    unsigned int u = v.u;
    return (unsigned short)((u + 0x7FFFu + ((u >> 16) & 1u)) >> 16);
}
__device__ __forceinline__ float bf2f(unsigned short h){
    union { unsigned int u; float f; } v; v.u = ((unsigned int)h) << 16;
    return v.f;
}
__device__ __forceinline__ float blo(unsigned int u){
    union { unsigned int u; float f; } v; v.u = u << 16; return v.f;
}
__device__ __forceinline__ float bhi(unsigned int u){
    union { unsigned int u; float f; } v; v.u = u & 0xffff0000u; return v.f;
}
__device__ __forceinline__ float i2f(int t){
    union { int i; float f; } v; v.i = t; return v.f;
}
__device__ __forceinline__ int f2i(float f){
    union { float f; int i; } v; v.f = f; return v.i;
}

// ---------- block ranges for prep_misc ----------
#define PB_CONV   1024
#define PB_NBR    1024
#define PB_W1     1536
#define PB_W2     1536
#define PB_BW      256
#define PB_ZERO    177
#define PB_ROUTER 1024
#define PB_TOTAL  (PB_CONV + PB_NBR + PB_W1 + PB_W2 + PB_BW + PB_ZERO + PB_ROUTER)
#define NZERO     45088

// All independent prep tasks in one launch (block-range dispatch).
__global__ __launch_bounds__(256) void prep_misc_kernel(
        const float* __restrict__ feature, const float* __restrict__ adj,
        const float* __restrict__ main_W1, const float* __restrict__ dep_W1,
        const float* __restrict__ main_W2, const float* __restrict__ dep_W2,
        const float* __restrict__ blend_W, const float* __restrict__ router_W,
        const int* __restrict__ doc_p, const int* __restrict__ sect_p,
        unsigned short* __restrict__ featbf, short* __restrict__ nbr,
        int4* __restrict__ nbc, unsigned short* __restrict__ w1nk,
        unsigned short* __restrict__ w2nk, unsigned short* __restrict__ bwt,
        float* __restrict__ zbase, float* __restrict__ rmask)
{
    int blk = blockIdx.x, tid = threadIdx.x;
    if (blk < PB_CONV){
        int idx = blk*256 + tid;                       // < ROWS*D/4
        float4 v = ((const float4*)feature)[idx];
        ushort4 o;
        o.x = f2bf(v.x); o.y = f2bf(v.y); o.z = f2bf(v.z); o.w = f2bf(v.w);
        ((ushort4*)featbf)[idx] = o;
        return;
    }
    blk -= PB_CONV;
    if (blk < PB_NBR){
        int wave = tid >> 6, lane = tid & 63;
        int row = blk*4 + wave;
        int b1 = S - *sect_p - *doc_p;
        int b2 = S - *doc_p;
        const float* ar = adj + (size_t)row*S + lane*16;
        float a[16];
        #pragma unroll
        for (int q = 0; q < 4; q++){
            float4 v = ((const float4*)ar)[q];
            a[q*4+0] = v.x; a[q*4+1] = v.y; a[q*4+2] = v.z; a[q*4+3] = v.w;
        }
        int t0 = lane*16;
        int k = 0, c1 = 0, c2 = 0;
        #pragma unroll
        for (int i = 0; i < 16; i++){
            if (a[i] > 0.f){
                k++;
                int t = t0 + i;
                if (t < b1) c1++;
                if (t < b2) c2++;
            }
        }
        int inc = k;
        #pragma unroll
        for (int d = 1; d < 64; d <<= 1){
            int u = __shfl_up(inc, d);
            if (lane >= d) inc += u;
        }
        int off = inc - k;
        int total = __shfl(inc, 63);
        int o = row*MAXN + off;
        #pragma unroll
        for (int i = 0; i < 16; i++){
            if (a[i] > 0.f) nbr[o++] = (short)(t0 + i);
        }
        for (int d = 32; d; d >>= 1){
            c1 += __shfl_down(c1, d);
            c2 += __shfl_down(c2, d);
        }
        if (lane == 0) nbc[row] = make_int4(total, c1, c2, 0);
        return;
    }
    blk -= PB_NBR;
    if (blk < PB_W1){
        int e = blk / 384;
        int idx = (blk - e*384)*256 + tid;             // < HHD*D
        const float* src = (e == 0) ? main_W1 : dep_W1 + (size_t)(e-1)*H*D*HD;
        int n = idx >> 8, k = idx & 255;
        int h = n >> 6, o = n & 63;
        w1nk[(size_t)e*HHD*D + idx] = f2bf(src[(h*D + k)*HD + o]);
        return;
    }
    blk -= PB_W1;
    if (blk < PB_W2){
        int g = blk*256 + tid;                         // < 4*D*HHD
        int e = g / (D*HHD);
        int rem = g - e*(D*HHD);
        int n = rem / HHD, k = rem - n*HHD;
        const float* src = (e == 0) ? main_W2 : dep_W2 + (size_t)(e-1)*HHD*D;
        w2nk[g] = f2bf(src[k*D + n]);
        return;
    }
    blk -= PB_W2;
    if (blk < PB_BW){
        int col = blk, k = tid;
        bwt[col*D + k] = f2bf(blend_W[k*D + col]);
        return;
    }
    blk -= PB_BW;
    if (blk < PB_ZERO){
        int idx = blk*256 + tid;
        if (idx < NZERO) zbase[idx] = 0.f;
        return;
    }
    blk -= PB_ZERO;
    {
        int wave = tid >> 6, lane = tid & 63;
        int row = blk*4 + wave;
        float4 xv = ((const float4*)(feature + (size_t)row*D))[lane];
        int f = lane*4;
        float xa[4] = {xv.x, xv.y, xv.z, xv.w};
        float p0 = 0.f, p1 = 0.f, p2 = 0.f;
        #pragma unroll
        for (int j = 0; j < 4; j++){
            p0 += xa[j]*router_W[(f+j)*NE + 0];
            p1 += xa[j]*router_W[(f+j)*NE + 1];
            p2 += xa[j]*router_W[(f+j)*NE + 2];
        }
        for (int off = 32; off; off >>= 1){
            p0 += __shfl_down(p0, off);
            p1 += __shfl_down(p1, off);
            p2 += __shfl_down(p2, off);
        }
        if (lane == 0){
            float p[3] = {p0, p1, p2};
            int ex = 0;
            for (int e = 1; e < NE; e++) if (p[e] <= p[ex]) ex = e;
            for (int e = 0; e < NE; e++) rmask[e*ROWS + row] = (e == ex) ? 0.f : 1.f;
        }
    }
}

// ---------- GEMM1 (x@W1) + fused es/ed + colmean; 128-wide M-tile (2 heads/block) ----------
// grid (3, ROWS/64, 5). z<4: expert slices; z==4: blend gate (x<2).
__global__ __launch_bounds__(256, 4) void gemm1_kernel(const unsigned short* __restrict__ w1nk,
                                                    const unsigned short* __restrict__ featbf,
                                                    const float* __restrict__ rmask,
                                                    const float* __restrict__ main_a1s,
                                                    const float* __restrict__ main_a1d,
                                                    const float* __restrict__ dep_a1s,
                                                    const float* __restrict__ dep_a1d,
                                                    const unsigned short* __restrict__ bwt,
                                                    const float* __restrict__ bb,
                                                    unsigned short* __restrict__ htn4,
                                                    float* __restrict__ es8,
                                                    float* __restrict__ ed8,
                                                    float* __restrict__ meanV1p,
                                                    float* __restrict__ gatebuf,
                                                    float* __restrict__ sumBuf){
    __shared__ float ep[2][2][64][17];      // [head][s/d][n][m-chunk]
    int tid = threadIdx.x, wave = tid >> 6, lane = tid & 63;
    int quad = lane >> 4, l16 = lane & 15;
    int e = blockIdx.z;
    int n0 = blockIdx.y*64;
    f32x4 z4 = {0.f,0.f,0.f,0.f};
    bf8_t bz = {0,0,0,0,0,0,0,0};

    if (e == 4){
        // ---- blend gate GEMM: gate[row][col] = sigmoid(x@blend_W + b), 128-wide m ----
        if (blockIdx.x >= 2) return;
        int m0 = blockIdx.x*128;
        const unsigned short* arow0 = bwt + (size_t)(m0 + wave*16 + l16)*D + quad*8;
        const unsigned short* arow1 = arow0 + (size_t)64*D;
        const unsigned short* brow[4];
        #pragma unroll
        for (int j = 0; j < 4; j++)
            brow[j] = featbf + (size_t)(n0 + j*16 + l16)*D + quad*8;
        f32x4 acc[8] = {z4, z4, z4, z4, z4, z4, z4, z4};
        bf8_t a0F = *(const bf8_t*)(arow0);
        bf8_t a1F = *(const bf8_t*)(arow1);
        bf8_t bF[4];
        #pragma unroll
        for (int j = 0; j < 4; j++) bF[j] = *(const bf8_t*)(brow[j]);
        #pragma unroll
        for (int it = 0; it < D/32; it++){
            bf8_t a0C = a0F, a1C = a1F;
            bf8_t bC[4] = {bF[0], bF[1], bF[2], bF[3]};
            if (it + 1 < D/32){
                int kn = (it + 1)*32;
                a0F = *(const bf8_t*)(arow0 + kn);
                a1F = *(const bf8_t*)(arow1 + kn);
                #pragma unroll
                for (int j = 0; j < 4; j++) bF[j] = *(const bf8_t*)(brow[j] + kn);
            }
            #pragma unroll
            for (int j = 0; j < 4; j++){
                acc[j]   = __builtin_amdgcn_mfma_f32_16x16x32_bf16(a0C, bC[j], acc[j],   0, 0, 0);
                acc[4+j] = __builtin_amdgcn_mfma_f32_16x16x32_bf16(a1C, bC[j], acc[4+j], 0, 0, 0);
            }
        }
        int mbase0 = m0 + wave*16 + quad*4;
        int mbase1 = mbase0 + 64;
        float bias0[4], bias1[4];
        #pragma unroll
        for (int r = 0; r < 4; r++){ bias0[r] = bb[mbase0 + r]; bias1[r] = bb[mbase1 + r]; }
        float lsum = 0.f;
        #pragma unroll
        for (int j = 0; j < 4; j++){
            int rown = n0 + j*16 + l16;
            f32x4 st0, st1;
            #pragma unroll
            for (int r = 0; r < 4; r++){
                float g0 = 1.f/(1.f + __expf(-(acc[j][r] + bias0[r])));
                float g1 = 1.f/(1.f + __expf(-(acc[4+j][r] + bias1[r])));
                lsum += g0 + g1;
                st0[r] = g0; st1[r] = g1;
            }
            *(f32x4*)(gatebuf + (size_t)rown*D + mbase0) = st0;
            *(f32x4*)(gatebuf + (size_t)rown*D + mbase1) = st1;
        }
        float* redp = &ep[0][0][0][0];
        redp[tid] = lsum;
        __syncthreads();
        for (int sft = 128; sft; sft >>= 1){
            if (tid < sft) redp[tid] += redp[tid + sft];
            __syncthreads();
        }
        if (tid == 0) atomicAdd(sumBuf, redp[0]);
        return;
    }

    // ---- expert slice: head pair p -> heads 2p, 2p+1 ----
    int p = blockIdx.x;
    int m0 = p*128;
    const unsigned short* arow0 = w1nk + (size_t)e*HHD*D + (size_t)(m0 + wave*16 + l16)*D + quad*8;
    const unsigned short* arow1 = arow0 + (size_t)64*D;
    const unsigned short* brow[4];
    bool zr[4];
    #pragma unroll
    for (int j = 0; j < 4; j++){
        int n = n0 + j*16 + l16;
        brow[j] = featbf + (size_t)n*D + quad*8;
        zr[j] = (e > 0) ? (rmask[(size_t)(e-1)*ROWS + n] == 0.f) : false;
    }
    f32x4 acc[8] = {z4, z4, z4, z4, z4, z4, z4, z4};
    bf8_t a0F = *(const bf8_t*)(arow0);
    bf8_t a1F = *(const bf8_t*)(arow1);
    bf8_t bF[4];
    #pragma unroll
    for (int j = 0; j < 4; j++) bF[j] = zr[j] ? bz : *(const bf8_t*)(brow[j]);
    #pragma unroll
    for (int it = 0; it < D/32; it++){
        bf8_t a0C = a0F, a1C = a1F;
        bf8_t bC[4] = {bF[0], bF[1], bF[2], bF[3]};
        if (it + 1 < D/32){
            int kn = (it + 1)*32;
            a0F = *(const bf8_t*)(arow0 + kn);
            a1F = *(const bf8_t*)(arow1 + kn);
            #pragma unroll
            for (int j = 0; j < 4; j++) bF[j] = zr[j] ? bz : *(const bf8_t*)(brow[j] + kn);
        }
        #pragma unroll
        for (int j = 0; j < 4; j++){
            acc[j]   = __builtin_amdgcn_mfma_f32_16x16x32_bf16(a0C, bC[j], acc[j],   0, 0, 0);
            acc[4+j] = __builtin_amdgcn_mfma_f32_16x16x32_bf16(a1C, bC[j], acc[4+j], 0, 0, 0);
        }
    }
    int b = n0 >> 10;
    int mbase0 = m0 + wave*16 + quad*4;
    int mbase1 = mbase0 + 64;
    int obase = wave*16 + quad*4;   // o within head (0..63)
    int h0 = p*2, h1 = p*2 + 1;
    #pragma unroll
    for (int j = 0; j < 4; j++){
        int row = n0 + j*16 + l16;
        ushort4 o0, o1;
        o0.x = f2bf(acc[j][0]);   o0.y = f2bf(acc[j][1]);
        o0.z = f2bf(acc[j][2]);   o0.w = f2bf(acc[j][3]);
        o1.x = f2bf(acc[4+j][0]); o1.y = f2bf(acc[4+j][1]);
        o1.z = f2bf(acc[4+j][2]); o1.w = f2bf(acc[4+j][3]);
        *(ushort4*)(htn4 + ((size_t)e*ROWS + row)*HHD + mbase0) = o0;
        *(ushort4*)(htn4 + ((size_t)e*ROWS + row)*HHD + mbase1) = o1;
    }
    const float* a1sp = (e == 0) ? main_a1s : dep_a1s + (size_t)(e-1)*H*HD;
    const float* a1dp = (e == 0) ? main_a1d : dep_a1d + (size_t)(e-1)*H*HD;
    float s0v[4], d0v[4], s1v[4], d1v[4];
    #pragma unroll
    for (int r = 0; r < 4; r++){
        s0v[r] = a1sp[mbase0 + r]; d0v[r] = a1dp[mbase0 + r];
        s1v[r] = a1sp[mbase1 + r]; d1v[r] = a1dp[mbase1 + r];
    }
    #pragma unroll
    for (int j = 0; j < 4; j++){
        float ps0 = 0.f, pd0 = 0.f, ps1 = 0.f, pd1 = 0.f;
        #pragma unroll
        for (int r = 0; r < 4; r++){
            ps0 += acc[j][r]*s0v[r];   pd0 += acc[j][r]*d0v[r];
            ps1 += acc[4+j][r]*s1v[r]; pd1 += acc[4+j][r]*d1v[r];
        }
        ep[0][0][j*16 + l16][wave*4 + quad] = ps0;
        ep[0][1][j*16 + l16][wave*4 + quad] = pd0;
        ep[1][0][j*16 + l16][wave*4 + quad] = ps1;
        ep[1][1][j*16 + l16][wave*4 + quad] = pd1;
    }
    float* mvb = meanV1p + ((size_t)e*B + b)*512;
    #pragma unroll
    for (int r = 0; r < 4; r++){
        float cm0 = acc[0][r] + acc[1][r] + acc[2][r] + acc[3][r];
        float cm1 = acc[4][r] + acc[5][r] + acc[6][r] + acc[7][r];
        for (int off = 8; off; off >>= 1){
            cm0 += __shfl_down(cm0, off, 16);
            cm1 += __shfl_down(cm1, off, 16);
        }
        if (l16 == 0){
            atomicAdd(mvb + (obase + r)*8 + h0, cm0*(1.f/(float)S));
            atomicAdd(mvb + (obase + r)*8 + h1, cm1*(1.f/(float)S));
        }
    }
    __syncthreads();
    {
        int hh = tid >> 7, arr = (tid >> 6) & 1, sl = tid & 63;
        float sum = 0.f;
        #pragma unroll
        for (int i = 0; i < 16; i++) sum += ep[hh][arr][sl][i];
        int n = n0 + sl;
        float* dst = arr ? ed8 : es8;
        dst[(((size_t)e*B + (n >> 10))*S + (n & 1023))*8 + (p*2 + hh)] = sum;
    }
}

// ---------- attn1 gather: one wave per (e,b,s), all 6 heads, direct htn4 reads ----------
// grid (S/4, 16)
__global__ __launch_bounds__(256) void attn1_gather_kernel(const unsigned short* __restrict__ htn4,
                                                           const float* __restrict__ es8,
                                                           const float* __restrict__ ed8,
                                                           const short* __restrict__ nbr,
                                                           const int4* __restrict__ nbc,
                                                           const float* __restrict__ meanV1p,
                                                           unsigned short* __restrict__ h1c4){
    __shared__ float wrec[4][MAXN][8];     // 16 KB
    int wave = threadIdx.x >> 6, lane = threadIdx.x & 63;
    int s = blockIdx.x*4 + wave;
    int e = blockIdx.y >> 2, b = blockIdx.y & 3;
    int row = b*S + s;
    int4 c = nbc[row];
    int lo = 0, hi = c.x;
    if (e == 1) hi = c.y;
    else if (e == 2){ lo = c.y; hi = c.z; }
    else if (e == 3){ lo = c.z; }
    int nn = hi - lo;
    const float* esp = es8 + (((size_t)e*B + b)*S + s)*8;
    f32x4 es_lo = *(const f32x4*)esp;
    f32x4 es_hi = *(const f32x4*)(esp + 4);
    float esv[6] = {es_lo[0], es_lo[1], es_lo[2], es_lo[3], es_hi[0], es_hi[1]};
    const float* edb = ed8 + (((size_t)e*B + b)*S)*8;
    const short* nl = nbr + (size_t)row*MAXN;
    float w0[6] = {0,0,0,0,0,0}, w1[6] = {0,0,0,0,0,0};
    int t0 = 0, t1 = 0;
    if (lane < nn){
        t0 = nl[lo + lane];
        const float* ep = edb + (size_t)t0*8;
        f32x4 d0 = *(const f32x4*)ep;
        f32x4 d1 = *(const f32x4*)(ep + 4);
        float edv[6] = {d0[0], d0[1], d0[2], d0[3], d1[0], d1[1]};
        #pragma unroll
        for (int h = 0; h < 6; h++) w0[h] = __expf(leaky(esv[h] + edv[h]));
    }
    if (64 + lane < nn){
        t1 = nl[lo + 64 + lane];
        const float* ep = edb + (size_t)t1*8;
        f32x4 d0 = *(const f32x4*)ep;
        f32x4 d1 = *(const f32x4*)(ep + 4);
        float edv[6] = {d0[0], d0[1], d0[2], d0[3], d1[0], d1[1]};
        #pragma unroll
        for (int h = 0; h < 6; h++) w1[h] = __expf(leaky(esv[h] + edv[h]));
    }
    float den[6];
    #pragma unroll
    for (int h = 0; h < 6; h++){
        float d = w0[h] + w1[h];
        for (int o2 = 32; o2; o2 >>= 1) d += __shfl_down(d, o2);
        den[h] = __shfl(d, 0);
    }
    if (lane < nn){
        f32x4 r0 = {w0[0], w0[1], w0[2], w0[3]};
        f32x4 r1 = {w0[4], w0[5], i2f(t0), 0.f};
        *(f32x4*)&wrec[wave][lane][0] = r0;
        *(f32x4*)&wrec[wave][lane][4] = r1;
    }
    if (64 + lane < nn){
        f32x4 r0 = {w1[0], w1[1], w1[2], w1[3]};
        f32x4 r1 = {w1[4], w1[5], i2f(t1), 0.f};
        *(f32x4*)&wrec[wave][64 + lane][0] = r0;
        *(f32x4*)&wrec[wave][64 + lane][4] = r1;
    }
    // direct htn4 reads: per neighbor, 6 coalesced 128B loads (imm offsets h*64)
    const unsigned short* Vb = htn4 + ((size_t)e*ROWS + b*S)*HHD + lane;
    float acc[6] = {0,0,0,0,0,0};
    #pragma unroll 4
    for (int j = 0; j < nn; j++){
        f32x4 r0 = *(const f32x4*)&wrec[wave][j][0];
        f32x4 r1 = *(const f32x4*)&wrec[wave][j][4];
        int t = f2i(r1[2]);
        const unsigned short* vp = Vb + (size_t)t*HHD;
        float v0 = bf2f(vp[0]);
        float v1 = bf2f(vp[64]);
        float v2 = bf2f(vp[128]);
        float v3 = bf2f(vp[192]);
        float v4 = bf2f(vp[256]);
        float v5 = bf2f(vp[320]);
        acc[0] += r0[0]*v0; acc[1] += r0[1]*v1;
        acc[2] += r0[2]*v2; acc[3] += r0[3]*v3;
        acc[4] += r1[0]*v4; acc[5] += r1[1]*v5;
    }
    unsigned short* outp = h1c4 + ((size_t)e*ROWS + row)*HHD;
    const float* mv = meanV1p + ((size_t)e*B + b)*512 + lane*8;
    #pragma unroll
    for (int h = 0; h < 6; h++){
        float v = (nn > 0) ? acc[h]/den[h] : mv[h];
        v = v > 0.f ? v : __expf(v) - 1.f;   // ELU
        outp[h*64 + lane] = f2bf(v);
    }
}

// ---------- GEMM2 (h1@W2) + fused f2s/f2d + colmean; 128-wide M-tile ----------
// grid (D/128=2, ROWS/64, 4experts). launch_bounds(256,4) + pipelined K-loop.
__global__ __launch_bounds__(256, 4) void gemm2_kernel(const unsigned short* __restrict__ w2nk,
                                                    const unsigned short* __restrict__ h1c4,
                                                    const float* __restrict__ main_a2s,
                                                    const float* __restrict__ main_a2d,
                                                    const float* __restrict__ dep_a2s,
                                                    const float* __restrict__ dep_a2d,
                                                    unsigned short* __restrict__ h2n4,
                                                    float* __restrict__ f2s4,
                                                    float* __restrict__ f2d4,
                                                    float* __restrict__ meanV2){
    __shared__ float ep[2][2][64][17];     // [m-half][s/d][n][m-chunk]
    int tid = threadIdx.x, wave = tid >> 6, lane = tid & 63;
    int quad = lane >> 4, l16 = lane & 15;
    int e = blockIdx.z;
    int m0 = blockIdx.x*128;
    int n0 = blockIdx.y*64;
    f32x4 z4 = {0.f,0.f,0.f,0.f};
    const unsigned short* arow0 = w2nk + (size_t)e*D*HHD + (size_t)(m0 + wave*16 + l16)*HHD + quad*8;
    const unsigned short* arow1 = arow0 + (size_t)64*HHD;
    const unsigned short* brow[4];
    #pragma unroll
    for (int j = 0; j < 4; j++)
        brow[j] = h1c4 + (size_t)e*ROWS*HHD + (size_t)(n0 + j*16 + l16)*HHD + quad*8;
    f32x4 acc[8] = {z4, z4, z4, z4, z4, z4, z4, z4};
    bf8_t a0F = *(const bf8_t*)(arow0);
    bf8_t a1F = *(const bf8_t*)(arow1);
    bf8_t bF[4];
    #pragma unroll
    for (int j = 0; j < 4; j++) bF[j] = *(const bf8_t*)(brow[j]);
    #pragma unroll
    for (int it = 0; it < HHD/32; it++){
        bf8_t a0C = a0F, a1C = a1F;
        bf8_t bC[4] = {bF[0], bF[1], bF[2], bF[3]};
        if (it + 1 < HHD/32){
            int kn = (it + 1)*32;
            a0F = *(const bf8_t*)(arow0 + kn);
            a1F = *(const bf8_t*)(arow1 + kn);
            #pragma unroll
            for (int j = 0; j < 4; j++) bF[j] = *(const bf8_t*)(brow[j] + kn);
        }
        #pragma unroll
        for (int j = 0; j < 4; j++){
            acc[j]   = __builtin_amdgcn_mfma_f32_16x16x32_bf16(a0C, bC[j], acc[j],   0, 0, 0);
            acc[4+j] = __builtin_amdgcn_mfma_f32_16x16x32_bf16(a1C, bC[j], acc[4+j], 0, 0, 0);
        }
    }
    int b = n0 >> 10;
    int mbase0 = m0 + wave*16 + quad*4;
    int mbase1 = mbase0 + 64;
    #pragma unroll
    for (int j = 0; j < 4; j++){
        int row = n0 + j*16 + l16;
        ushort4 o0, o1;
        o0.x = f2bf(acc[j][0]);   o0.y = f2bf(acc[j][1]);
        o0.z = f2bf(acc[j][2]);   o0.w = f2bf(acc[j][3]);
        o1.x = f2bf(acc[4+j][0]); o1.y = f2bf(acc[4+j][1]);
        o1.z = f2bf(acc[4+j][2]); o1.w = f2bf(acc[4+j][3]);
        *(ushort4*)(h2n4 + ((size_t)e*ROWS + row)*D + mbase0) = o0;
        *(ushort4*)(h2n4 + ((size_t)e*ROWS + row)*D + mbase1) = o1;
    }
    const float* a2sp = (e == 0) ? main_a2s : dep_a2s + (size_t)(e-1)*D;
    const float* a2dp = (e == 0) ? main_a2d : dep_a2d + (size_t)(e-1)*D;
    float s0v[4], d0v[4], s1v[4], d1v[4];
    #pragma unroll
    for (int r = 0; r < 4; r++){
        s0v[r] = a2sp[mbase0 + r]; d0v[r] = a2dp[mbase0 + r];
        s1v[r] = a2sp[mbase1 + r]; d1v[r] = a2dp[mbase1 + r];
    }
    #pragma unroll
    for (int j = 0; j < 4; j++){
        float ps0 = 0.f, pd0 = 0.f, ps1 = 0.f, pd1 = 0.f;
        #pragma unroll
        for (int r = 0; r < 4; r++){
            ps0 += acc[j][r]*s0v[r];   pd0 += acc[j][r]*d0v[r];
            ps1 += acc[4+j][r]*s1v[r]; pd1 += acc[4+j][r]*d1v[r];
        }
        ep[0][0][j*16 + l16][wave*4 + quad] = ps0;
        ep[0][1][j*16 + l16][wave*4 + quad] = pd0;
        ep[1][0][j*16 + l16][wave*4 + quad] = ps1;
        ep[1][1][j*16 + l16][wave*4 + quad] = pd1;
    }
    #pragma unroll
    for (int r = 0; r < 4; r++){
        float cm0 = acc[0][r] + acc[1][r] + acc[2][r] + acc[3][r];
        float cm1 = acc[4][r] + acc[5][r] + acc[6][r] + acc[7][r];
        for (int off = 8; off; off >>= 1){
            cm0 += __shfl_down(cm0, off, 16);
            cm1 += __shfl_down(cm1, off, 16);
        }
        if (l16 == 0){
            atomicAdd(meanV2 + ((size_t)e*B + b)*D + mbase0 + r, cm0*(1.f/(float)S));
            atomicAdd(meanV2 + ((size_t)e*B + b)*D + mbase1 + r, cm1*(1.f/(float)S));
        }
    }
    __syncthreads();
    {
        int hh = tid >> 7, arr = (tid >> 6) & 1, sl = tid & 63;
        float sum = 0.f;
        #pragma unroll
        for (int i = 0; i < 16; i++) sum += ep[hh][arr][sl][i];
        int n = n0 + sl;
        float* dst = arr ? f2d4 : f2s4;
        atomicAdd(dst + (size_t)e*ROWS + n, sum);
    }
}

// ---------- attn2 + blend: one block per (b,s); wave = expert; combine in LDS ----------
// grid (S, B)
__global__ __launch_bounds__(256) void attn2_blend_kernel(const unsigned short* __restrict__ h2n4,
                                                          const float* __restrict__ f2s4,
                                                          const float* __restrict__ f2d4,
                                                          const short* __restrict__ nbr,
                                                          const int4* __restrict__ nbc,
                                                          const float* __restrict__ meanV2,
                                                          const float* __restrict__ gatebuf,
                                                          const float* __restrict__ rmask,
                                                          const float* __restrict__ sumBuf,
                                                          float* __restrict__ outp){
    __shared__ float2 wrec[4][MAXN];       // 4 KB
    __shared__ float outs[4][256];         // 4 KB
    int wave = threadIdx.x >> 6, lane = threadIdx.x & 63;
    int s = blockIdx.x, b = blockIdx.y;
    int e = wave;                           // wave = expert
    int row = b*S + s;
    int4 c = nbc[row];
    int lo = 0, hi = c.x;
    if (e == 1) hi = c.y;
    else if (e == 2){ lo = c.y; hi = c.z; }
    else if (e == 3){ lo = c.z; }
    int nn = hi - lo;
    float fs_r = f2s4[(size_t)e*ROWS + row];
    const float* fdp = f2d4 + (size_t)e*ROWS + b*S;
    const short* nl = nbr + (size_t)row*MAXN;
    float w0 = 0.f, w1 = 0.f;
    int t0 = 0, t1 = 0;
    if (lane < nn){ t0 = nl[lo + lane]; w0 = __expf(leaky(fs_r + fdp[t0])); }
    if (64 + lane < nn){ t1 = nl[lo + 64 + lane]; w1 = __expf(leaky(fs_r + fdp[t1])); }
    float den = w0 + w1;
    for (int o2 = 32; o2; o2 >>= 1) den += __shfl_down(den, o2);
    den = __shfl(den, 0);
    if (lane < nn){ float2 r; r.x = w0; r.y = i2f(t0); wrec[wave][lane] = r; }
    if (64 + lane < nn){ float2 r; r.x = w1; r.y = i2f(t1); wrec[wave][64 + lane] = r; }
    const unsigned short* V = h2n4 + ((size_t)e*ROWS + b*S)*D;
    float acc[4] = {0,0,0,0};
    #pragma unroll 4
    for (int j = 0; j < nn; j++){
        float2 r = wrec[wave][j];
        float w = r.x;
        int t = f2i(r.y);
        const unsigned short* vp = V + (size_t)t*D + lane*4;
        uint2 dv = *(const uint2*)vp;
        acc[0] += w*blo(dv.x); acc[1] += w*bhi(dv.x);
        acc[2] += w*blo(dv.y); acc[3] += w*bhi(dv.y);
    }
    if (nn > 0){
        float inv = 1.f/den;
        #pragma unroll
        for (int q = 0; q < 4; q++) outs[e][lane*4 + q] = acc[q]*inv;
    } else {
        const float* mv = meanV2 + ((size_t)e*B + b)*D + lane*4;
        #pragma unroll
        for (int q = 0; q < 4; q++) outs[e][lane*4 + q] = mv[q];
    }
    __syncthreads();
    // combine: thread tid = col
    int col = threadIdx.x;
    float g = gatebuf[(size_t)row*D + col];
    float rm0 = rmask[row], rm1 = rmask[ROWS + row], rm2 = rmask[2*ROWS + row];
    float dep = rm0*outs[1][col] + rm1*outs[2][col] + rm2*outs[3][col];
    outp[(size_t)row*D + col] = g*outs[0][col] + (1.f - g)*dep;
    if (blockIdx.x == 0 && blockIdx.y == 0 && threadIdx.x == 0){
        float mc = sumBuf[0] / (float)(ROWS*D);   // filled during gemm1 gate pass
        outp[ROWS*D]     = fabsf(mc - 0.6f)*0.01f;
        outp[ROWS*D + 1] = mc;
    }
}

extern "C" void kernel_launch(void* const* d_in, const int* in_sizes, int n_in,
                              void* d_out, int out_size, void* d_ws, size_t ws_size,
                              hipStream_t stream)
{
    const float* feature  = (const float*)d_in[0];
    const float* adj      = (const float*)d_in[1];
    const float* main_W1  = (const float*)d_in[2];
    const float* main_a1s = (const float*)d_in[3];
    const float* main_a1d = (const float*)d_in[4];
    const float* main_W2  = (const float*)d_in[5];
    const float* main_a2s = (const float*)d_in[6];
    const float* main_a2d = (const float*)d_in[7];
    const float* dep_W1   = (const float*)d_in[8];
    const float* dep_a1s  = (const float*)d_in[9];
    const float* dep_a1d  = (const float*)d_in[10];
    const float* dep_W2   = (const float*)d_in[11];
    const float* dep_a2s  = (const float*)d_in[12];
    const float* dep_a2d  = (const float*)d_in[13];
    const float* router_W = (const float*)d_in[14];
    const float* blend_W  = (const float*)d_in[15];
    const float* blend_b  = (const float*)d_in[16];
    const int*   doc_p    = (const int*)d_in[17];
    const int*   sect_p   = (const int*)d_in[18];

    char* ws = (char*)d_ws;
    size_t off = 0;
    unsigned short* featbf = (unsigned short*)(ws + off); off += (size_t)ROWS*D*2;        // 2 MB
    short*          nbr    = (short*)(ws + off);          off += (size_t)ROWS*MAXN*2;     // 1 MB
    int4*           nbc    = (int4*)(ws + off);           off += (size_t)ROWS*16;         // 64 KB
    unsigned short* w1nk   = (unsigned short*)(ws + off); off += (size_t)4*HHD*D*2;
    unsigned short* w2nk   = (unsigned short*)(ws + off); off += (size_t)4*D*HHD*2;
    unsigned short* bwt    = (unsigned short*)(ws + off); off += (size_t)D*D*2;
    float* es8 = (float*)(ws + off); off += (size_t)4*B*S*8*4;   // 512 KB
    float* ed8 = (float*)(ws + off); off += (size_t)4*B*S*8*4;   // 512 KB
    float* gatebuf = (float*)(ws + off); off += (size_t)ROWS*D*4;                         // 4 MB
    // region A: htn (12 MB)
    unsigned short* htn4 = (unsigned short*)(ws + off); off += (size_t)4*ROWS*HHD*2;
    // region C: h2n4 (8 MB)
    unsigned short* h2n4 = (unsigned short*)(ws + off); off += (size_t)4*ROWS*D*2;
    unsigned short* h1c4 = (unsigned short*)(ws + off); off += (size_t)4*ROWS*HHD*2;      // 12 MB
    // contiguous zero region (NZERO floats):
    float* f2s4    = (float*)(ws + off); off += (size_t)4*ROWS*4;
    float* f2d4    = (float*)(ws + off); off += (size_t)4*ROWS*4;
    float* meanV1p = (float*)(ws + off); off += (size_t)4*B*512*4;
    float* meanV2  = (float*)(ws + off); off += (size_t)4*B*D*4;
    float* sumBuf  = (float*)(ws + off); off += 128;
    float* rmask   = (float*)(ws + off); off += (size_t)NE*ROWS*4;
    float* outp    = (float*)d_out;

    prep_misc_kernel<<<PB_TOTAL, 256, 0, stream>>>(
        feature, adj, main_W1, dep_W1, main_W2, dep_W2, blend_W, router_W,
        doc_p, sect_p, featbf, nbr, nbc, w1nk, w2nk, bwt, f2s4, rmask);

    gemm1_kernel<<<dim3(3, ROWS/64, 5), 256, 0, stream>>>(w1nk, featbf, rmask,
        main_a1s, main_a1d, dep_a1s, dep_a1d, bwt, blend_b,
        htn4, es8, ed8, meanV1p, gatebuf, sumBuf);
    attn1_gather_kernel<<<dim3(S/4, 16), 256, 0, stream>>>(htn4, es8, ed8, nbr, nbc,
        meanV1p, h1c4);
    gemm2_kernel<<<dim3(D/128, ROWS/64, 4), 256, 0, stream>>>(w2nk, h1c4,
        main_a2s, main_a2d, dep_a2s, dep_a2d, h2n4, f2s4, f2d4, meanV2);
    attn2_blend_kernel<<<dim3(S, B), 256, 0, stream>>>(h2n4, f2s4, f2d4, nbr, nbc,
        meanV2, gatebuf, rmask, sumBuf, outp);
}